// Round 7
// baseline (208.952 us; speedup 1.0000x reference)
//
#include <hip/hip_runtime.h>
#include <hip/hip_bf16.h>

typedef __attribute__((ext_vector_type(8))) short short8;
typedef __attribute__((ext_vector_type(4))) float floatx4;
typedef __attribute__((ext_vector_type(8))) unsigned short ushortx8;
typedef __attribute__((ext_vector_type(4))) unsigned short ushortx4;
typedef unsigned short u16;

#define NH 16
#define SEQ 2048
#define CHUNK 128
#define NCHUNK 16

__device__ __forceinline__ u16 f2bf(float f) {
    union { float f; unsigned u; } v; v.f = f;
    unsigned r = v.u + 0x7fffu + ((v.u >> 16) & 1u);
    return (u16)(r >> 16);
}
__device__ __forceinline__ float bf2f(u16 u) {
    union { unsigned u; float f; } v; v.u = ((unsigned)u) << 16;
    return v.f;
}
__device__ __forceinline__ void gl_lds16(const u16* g, u16* l) {
    __builtin_amdgcn_global_load_lds(
        (const __attribute__((address_space(1))) void*)g,
        (__attribute__((address_space(3))) void*)l,
        16, 0, 0);
}

// ---------------------------------------------------------------------------
// Kernel 0: fp32 -> bf16 of x, Wq|Wk|Wv (fused rows), Wo. ~36 MB traffic.
// ---------------------------------------------------------------------------
__global__ __launch_bounds__(256)
void convert_all(const float* __restrict__ x,  const float* __restrict__ Wq,
                 const float* __restrict__ Wk, const float* __restrict__ Wv,
                 const float* __restrict__ Wo,
                 u16* __restrict__ xb, u16* __restrict__ Wb, u16* __restrict__ Wob)
{
    const int total4 = 1572864;  // 6M floats / 4
    for (int idx = blockIdx.x * 256 + threadIdx.x; idx < total4; idx += gridDim.x * 256) {
        const float4* src; u16* dst; int off;
        if (idx < 524288)       { src = (const float4*)x;  dst = xb;            off = idx; }
        else if (idx < 786432)  { src = (const float4*)Wq; dst = Wb;            off = idx - 524288; }
        else if (idx < 1048576) { src = (const float4*)Wk; dst = Wb + 1048576;  off = idx - 786432; }
        else if (idx < 1310720) { src = (const float4*)Wv; dst = Wb + 2097152;  off = idx - 1048576; }
        else                    { src = (const float4*)Wo; dst = Wob;           off = idx - 1310720; }
        float4 v = src[off];
        ushortx4 u = { f2bf(v.x), f2bf(v.y), f2bf(v.z), f2bf(v.w) };
        *(ushortx4*)(dst + (size_t)off * 4) = u;
    }
}

// ---------------------------------------------------------------------------
// Kernel 1: fused QKV GEMM, 64x128 tile (768 blocks = 3/CU), BK=64 (R3 body).
// MEASUREMENT ROUND: launched 5x back-to-back (idempotent) so
// qkv_warm = (dur_us - 132.3) / 4. Body unchanged from R6.
// ---------------------------------------------------------------------------
__global__ __launch_bounds__(256, 3)
void qkv_gemm64(const u16* __restrict__ A, const u16* __restrict__ Bm,
                u16* __restrict__ qkb, u16* __restrict__ kT_b, u16* __restrict__ vT_b)
{
    __shared__ u16 As[64 * 64];
    __shared__ u16 Bs[128 * 64];
    const int n0 = blockIdx.x * 128, m0 = blockIdx.y * 64;
    const int t = threadIdx.x;
    const int lane = t & 63, wave = t >> 6;
    const int ln = lane & 15, q4 = lane >> 4;
    const int wm = (wave >> 1) * 32, wn = (wave & 1) * 64;
    const int r_in = t >> 3;
    const int csw = (((t & 7) ^ (r_in & 7)) << 3);

    const u16* Ag = A + (size_t)(m0 + r_in) * 1024 + csw;
    const u16* Bg = Bm + (size_t)(n0 + r_in) * 1024 + csw;

    floatx4 acc[2][4];
#pragma unroll
    for (int i = 0; i < 2; i++)
#pragma unroll
        for (int j = 0; j < 4; j++) acc[i][j] = (floatx4)0.0f;

    for (int k0 = 0; k0 < 1024; k0 += 64) {
        if (k0) __syncthreads();
        gl_lds16(Ag, &As[t * 8]);
        gl_lds16(Ag + 32 * 1024, &As[2048 + t * 8]);
#pragma unroll
        for (int i = 0; i < 4; i++)
            gl_lds16(Bg + (size_t)i * 32 * 1024, &Bs[i * 2048 + t * 8]);
        Ag += 64; Bg += 64;
        __syncthreads();
#pragma unroll
        for (int s = 0; s < 2; s++) {
            const int rc = (((s * 4 + q4) ^ (ln & 7)) << 3);
            short8 af[2], bfr[4];
#pragma unroll
            for (int i = 0; i < 2; i++)
                af[i] = *(const short8*)&As[(wm + i * 16 + ln) * 64 + rc];
#pragma unroll
            for (int j = 0; j < 4; j++)
                bfr[j] = *(const short8*)&Bs[(wn + j * 16 + ln) * 64 + rc];
#pragma unroll
            for (int i = 0; i < 2; i++)
#pragma unroll
                for (int j = 0; j < 4; j++)
                    acc[i][j] = __builtin_amdgcn_mfma_f32_16x16x32_bf16(af[i], bfr[j], acc[i][j], 0, 0, 0);
        }
    }
    const int grp = n0 >> 10;  // 0=q 1=k 2=v (block-uniform)
#pragma unroll
    for (int i = 0; i < 2; i++)
#pragma unroll
        for (int j = 0; j < 4; j++) {
            const int mb = m0 + wm + i * 16 + q4 * 4;
            const int n = n0 + wn + j * 16 + ln;
            const int nh = n & 1023, h = nh >> 6, e = nh & 63;
            float vals[4];
#pragma unroll
            for (int r = 0; r < 4; r++) {
                float v = acc[i][j][r];
                if (grp < 2) v = (v > 0.f) ? (v + 1.f) : __expf(v);
                vals[r] = v;
            }
            if (grp == 0) {
#pragma unroll
                for (int r = 0; r < 4; r++) qkb[(size_t)(mb + r) * 2048 + nh] = f2bf(vals[r]);
            } else if (grp == 1) {
#pragma unroll
                for (int r = 0; r < 4; r++) qkb[(size_t)(mb + r) * 2048 + 1024 + nh] = f2bf(vals[r]);
                ushortx4 u = { f2bf(vals[0]), f2bf(vals[1]), f2bf(vals[2]), f2bf(vals[3]) };
                *(ushortx4*)&kT_b[(size_t)(h * 64 + e) * 2048 + mb] = u;
            } else {
                ushortx4 u = { f2bf(vals[0]), f2bf(vals[1]), f2bf(vals[2]), f2bf(vals[3]) };
                *(ushortx4*)&vT_b[(size_t)(h * 64 + e) * 2048 + mb] = u;
            }
        }
}

// ---------------------------------------------------------------------------
// Kernel 2: FUSED chunk-state + attention per (c,h). grid (16,16). (R6 body)
// ---------------------------------------------------------------------------
__global__ __launch_bounds__(256, 1)
void attn_fused(const u16* __restrict__ qkb, const u16* __restrict__ kT_b,
                const u16* __restrict__ vT_b, u16* __restrict__ attnb)
{
    __shared__ __align__(16) u16 smem[29824];   // 59648 B
    u16* kT_s  = smem;           // [64][128]  phase-A staging
    u16* vT_s  = smem + 8192;    // [64][128]  phase-A staging
    u16* vT_l  = smem;           // [64][128]  own chunk (over kT_s)
    u16* q_l   = smem + 8192;    // [128][64]  (over vT_s)
    u16* k_l   = smem + 16384;   // [128][64]
    u16* P_l   = smem + 8192;    // [128][128] swizzled (over q_l+k_l when dead)
    u16* kvT_l = smem + 24576;   // [64][72]
    float* kpref  = (float*)(smem + 29184);  // [64]
    float* denom2 = (float*)(smem + 29312);  // [2][128]

    const int c = blockIdx.x, h = blockIdx.y;
    const int t = threadIdx.x;
    const int lane = t & 63, w = t >> 6;
    const int ln = lane & 15, q4 = lane >> 4;

    // ---- phase A: prefix KV state + kpref over chunks 0..c-1 ----
    floatx4 sacc[4];
    floatx4 sksum = (floatx4)0.0f;
#pragma unroll
    for (int j = 0; j < 4; j++) sacc[j] = (floatx4)0.0f;
    const short one_bf = (short)0x3F80;
    const short8 a_ones = { one_bf, one_bf, one_bf, one_bf,
                            one_bf, one_bf, one_bf, one_bf };
    for (int cp = 0; cp < c; cp++) {
        __syncthreads();               // prev chunk's LDS reads done
#pragma unroll
        for (int i = 0; i < 4; i++) {
            const int d0 = w * 16 + i * 4 + (lane >> 4);
            const int cc = lane & 15;
            const size_t gsrc = (size_t)(h * 64 + d0) * 2048 + cp * 128 + ((cc ^ (d0 & 7)) << 3);
            gl_lds16(kT_b + gsrc, &kT_s[(w * 16 + i * 4) * 128 + lane * 8]);
            gl_lds16(vT_b + gsrc, &vT_s[(w * 16 + i * 4) * 128 + lane * 8]);
        }
        __syncthreads();               // drain DMA
#pragma unroll
        for (int ks = 0; ks < 4; ks++) {
            const int rc = (((ks * 4 + q4) ^ (ln & 7)) << 3);
            short8 af = *(const short8*)&kT_s[(w * 16 + ln) * 128 + rc];
            sksum = __builtin_amdgcn_mfma_f32_16x16x32_bf16(a_ones, af, sksum, 0, 0, 0);
#pragma unroll
            for (int j = 0; j < 4; j++) {
                short8 bfr = *(const short8*)&vT_s[(j * 16 + ln) * 128 + rc];
                sacc[j] = __builtin_amdgcn_mfma_f32_16x16x32_bf16(af, bfr, sacc[j], 0, 0, 0);
            }
        }
    }
    __syncthreads();                   // phase-A LDS reads done; regions reusable

    // ---- own-chunk staging (async) + publish kvT/kpref ----
#pragma unroll
    for (int i = 0; i < 4; i++) {
        const int l = i * 32 + w * 8 + (lane >> 3);
        const int cc = lane & 7;
        const size_t gq = (size_t)(c * CHUNK + l) * 2048 + h * 64 + ((cc ^ (l & 7)) << 3);
        gl_lds16(qkb + gq,        &q_l[(i * 32 + w * 8) * 64 + lane * 8]);
        gl_lds16(qkb + gq + 1024, &k_l[(i * 32 + w * 8) * 64 + lane * 8]);
        const int d0 = w * 16 + i * 4 + (lane >> 4);
        const int cv = lane & 15;
        gl_lds16(vT_b + (size_t)(h * 64 + d0) * 2048 + c * 128 + ((cv ^ (d0 & 7)) << 3),
                 &vT_l[(w * 16 + i * 4) * 128 + lane * 8]);
    }
    // kvT_l[e][d] = KV_pref[d][e]
#pragma unroll
    for (int j = 0; j < 4; j++) {
        const int e = j * 16 + ln;
        ushortx4 u = { f2bf(sacc[j][0]), f2bf(sacc[j][1]), f2bf(sacc[j][2]), f2bf(sacc[j][3]) };
        *(ushortx4*)&kvT_l[e * 72 + w * 16 + q4 * 4] = u;
    }
    if (q4 == 0) kpref[w * 16 + ln] = sksum[0];  // ones-MFMA: col d = w*16+ln
    __syncthreads();                   // drains own DMAs; kvT/kpref visible

    // ---- P = QK^T : wave quadrant, 64x64, K=64 ----
    const int pm = (w >> 1) * 64, pn = (w & 1) * 64;
    floatx4 pacc[4][4];
#pragma unroll
    for (int i = 0; i < 4; i++)
#pragma unroll
        for (int j = 0; j < 4; j++) pacc[i][j] = (floatx4)0.0f;
#pragma unroll
    for (int s = 0; s < 2; s++) {
        const int rc = (((s * 4 + q4) ^ (ln & 7)) << 3);
        short8 af[4], bfr[4];
#pragma unroll
        for (int i = 0; i < 4; i++)
            af[i] = *(const short8*)&q_l[(pm + i * 16 + ln) * 64 + rc];
#pragma unroll
        for (int j = 0; j < 4; j++)
            bfr[j] = *(const short8*)&k_l[(pn + j * 16 + ln) * 64 + rc];
#pragma unroll
        for (int i = 0; i < 4; i++)
#pragma unroll
            for (int j = 0; j < 4; j++)
                pacc[i][j] = __builtin_amdgcn_mfma_f32_16x16x32_bf16(af[i], bfr[j], pacc[i][j], 0, 0, 0);
    }
    // ---- causal mask + rowsum (intra denominator) ----
#pragma unroll
    for (int i = 0; i < 4; i++)
#pragma unroll
        for (int r = 0; r < 4; r++) {
            int rowi = pm + i * 16 + q4 * 4 + r;
            float rs = 0.f;
#pragma unroll
            for (int j = 0; j < 4; j++) {
                int col = pn + j * 16 + ln;
                float p = pacc[i][j][r];
                if (col > rowi) p = 0.f;
                pacc[i][j][r] = p;
                rs += p;
            }
#pragma unroll
            for (int off = 1; off < 16; off <<= 1) rs += __shfl_xor(rs, off, 64);
            if (ln == 0) denom2[(w & 1) * 128 + rowi] = rs;
        }
    // ---- O_inter = Q @ KV_pref ----
    const int ob = w * 32;
    floatx4 oacc[2][4];
#pragma unroll
    for (int i = 0; i < 2; i++)
#pragma unroll
        for (int j = 0; j < 4; j++) oacc[i][j] = (floatx4)0.0f;
#pragma unroll
    for (int s = 0; s < 2; s++) {
        const int rc = (((s * 4 + q4) ^ (ln & 7)) << 3);
        short8 af[2], bfr[4];
#pragma unroll
        for (int i2 = 0; i2 < 2; i2++)
            af[i2] = *(const short8*)&q_l[(ob + i2 * 16 + ln) * 64 + rc];
#pragma unroll
        for (int j = 0; j < 4; j++)
            bfr[j] = *(const short8*)&kvT_l[(j * 16 + ln) * 72 + s * 32 + q4 * 8];
#pragma unroll
        for (int i2 = 0; i2 < 2; i2++)
#pragma unroll
            for (int j = 0; j < 4; j++)
                oacc[i2][j] = __builtin_amdgcn_mfma_f32_16x16x32_bf16(af[i2], bfr[j], oacc[i2][j], 0, 0, 0);
    }
    __syncthreads();   // denom rowsums visible; q/k/kvT MFMA reads done
    // ---- denominator inter part: q_i . kpref ----
    if (t < 128) {
        float s = 0.f;
#pragma unroll
        for (int c8 = 0; c8 < 8; c8++) {
            ushortx8 v8 = *(const ushortx8*)&q_l[t * 64 + ((c8 ^ (t & 7)) << 3)];
#pragma unroll
            for (int jj = 0; jj < 8; jj++) s += bf2f(v8[jj]) * kpref[c8 * 8 + jj];
        }
        denom2[t] += s;
    }
    __syncthreads();   // q_l reads done; safe to overwrite with P
    // ---- write masked P, bf16, XOR-swizzled [128][128] ----
#pragma unroll
    for (int i = 0; i < 4; i++)
#pragma unroll
        for (int j = 0; j < 4; j++)
#pragma unroll
            for (int r = 0; r < 4; r++) {
                int rowi = pm + i * 16 + q4 * 4 + r;
                int col = pn + j * 16 + ln;
                P_l[rowi * 128 + (col ^ ((rowi & 7) << 3))] = f2bf(pacc[i][j][r]);
            }
    __syncthreads();
    // ---- O_intra = P @ V : causal skip (ks <= wave) ----
    for (int ks = 0; ks <= w; ks++) {
        short8 af[2], bfr[4];
#pragma unroll
        for (int i2 = 0; i2 < 2; i2++) {
            const int row = ob + i2 * 16 + ln;
            af[i2] = *(const short8*)&P_l[row * 128 + ((((ks * 4 + q4) ^ (row & 7))) << 3)];
        }
        const int rc = (((ks * 4 + q4) ^ (ln & 7)) << 3);
#pragma unroll
        for (int j = 0; j < 4; j++)
            bfr[j] = *(const short8*)&vT_l[(j * 16 + ln) * 128 + rc];
#pragma unroll
        for (int i2 = 0; i2 < 2; i2++)
#pragma unroll
            for (int j = 0; j < 4; j++)
                oacc[i2][j] = __builtin_amdgcn_mfma_f32_16x16x32_bf16(af[i2], bfr[j], oacc[i2][j], 0, 0, 0);
    }
    // ---- normalize + store ----
#pragma unroll
    for (int i2 = 0; i2 < 2; i2++)
#pragma unroll
        for (int j = 0; j < 4; j++)
#pragma unroll
            for (int r = 0; r < 4; r++) {
                int rowi = ob + i2 * 16 + q4 * 4 + r;
                int e = j * 16 + ln;
                float den = denom2[rowi] + denom2[128 + rowi];
                den = fmaxf(den, 1e-6f);
                float val = oacc[i2][j][r] / den;
                attnb[(size_t)(c * CHUNK + rowi) * 1024 + h * 64 + e] = f2bf(val);
            }
}

// ---------------------------------------------------------------------------
// Kernel 3: out = attn @ Wo^T, 64x64 tile (512 blocks = 2/CU), fp32 out.
// ---------------------------------------------------------------------------
__global__ __launch_bounds__(256, 3)
void out_gemm64(const u16* __restrict__ A, const u16* __restrict__ Bm,
                float* __restrict__ out)
{
    __shared__ u16 As[64 * 64];
    __shared__ u16 Bs[64 * 64];
    const int n0 = blockIdx.x * 64, m0 = blockIdx.y * 64;
    const int t = threadIdx.x;
    const int lane = t & 63, wave = t >> 6;
    const int ln = lane & 15, q4 = lane >> 4;
    const int wm = (wave >> 1) * 32, wn = (wave & 1) * 32;
    const int r_in = t >> 3;
    const int csw = (((t & 7) ^ (r_in & 7)) << 3);

    const u16* Ag = A + (size_t)(m0 + r_in) * 1024 + csw;
    const u16* Bg = Bm + (size_t)(n0 + r_in) * 1024 + csw;

    floatx4 acc[2][2];
#pragma unroll
    for (int i = 0; i < 2; i++)
#pragma unroll
        for (int j = 0; j < 2; j++) acc[i][j] = (floatx4)0.0f;

    for (int k0 = 0; k0 < 1024; k0 += 64) {
        if (k0) __syncthreads();
        gl_lds16(Ag, &As[t * 8]);
        gl_lds16(Ag + 32 * 1024, &As[2048 + t * 8]);
        gl_lds16(Bg, &Bs[t * 8]);
        gl_lds16(Bg + 32 * 1024, &Bs[2048 + t * 8]);
        Ag += 64; Bg += 64;
        __syncthreads();
#pragma unroll
        for (int s = 0; s < 2; s++) {
            const int rc = (((s * 4 + q4) ^ (ln & 7)) << 3);
            short8 af[2], bfr[2];
#pragma unroll
            for (int i = 0; i < 2; i++)
                af[i] = *(const short8*)&As[(wm + i * 16 + ln) * 64 + rc];
#pragma unroll
            for (int j = 0; j < 2; j++)
                bfr[j] = *(const short8*)&Bs[(wn + j * 16 + ln) * 64 + rc];
#pragma unroll
            for (int i = 0; i < 2; i++)
#pragma unroll
                for (int j = 0; j < 2; j++)
                    acc[i][j] = __builtin_amdgcn_mfma_f32_16x16x32_bf16(af[i], bfr[j], acc[i][j], 0, 0, 0);
        }
    }
#pragma unroll
    for (int i = 0; i < 2; i++)
#pragma unroll
        for (int j = 0; j < 2; j++)
#pragma unroll
            for (int r = 0; r < 4; r++) {
                int m = m0 + wm + i * 16 + q4 * 4 + r;
                int n = n0 + wn + j * 16 + ln;
                out[(size_t)m * 1024 + n] = acc[i][j][r];
            }
}

// ---------------------------------------------------------------------------
// Workspace (32 MB of >=256 MB):
//   xb @ 0 (4MB) | Wb @ 4 (6MB) | Wob @ 10 (2MB) | qkb @ 12 (8MB)
//   kT_b @ 20 (4MB) | vT_b @ 24 (4MB) | attnb @ 28 (4MB)
// ---------------------------------------------------------------------------
extern "C" void kernel_launch(void* const* d_in, const int* in_sizes, int n_in,
                              void* d_out, int out_size, void* d_ws, size_t ws_size,
                              hipStream_t stream)
{
    const float* x  = (const float*)d_in[0];
    const float* Wq = (const float*)d_in[1];
    const float* Wk = (const float*)d_in[2];
    const float* Wv = (const float*)d_in[3];
    const float* Wo = (const float*)d_in[4];
    float* out = (float*)d_out;

    char* ws = (char*)d_ws;
    const size_t MB = 1024 * 1024;
    u16* xb    = (u16*)(ws);
    u16* Wb    = (u16*)(ws + 4 * MB);
    u16* Wob   = (u16*)(ws + 10 * MB);
    u16* qkb   = (u16*)(ws + 12 * MB);
    u16* kT_b  = (u16*)(ws + 20 * MB);
    u16* vT_b  = (u16*)(ws + 24 * MB);
    u16* attnb = (u16*)(ws + 28 * MB);

    convert_all<<<2048, 256, 0, stream>>>(x, Wq, Wk, Wv, Wo, xb, Wb, Wob);
    // MEASUREMENT: 5x identical launches (idempotent). qkv = (dur - 132.3)/4.
    qkv_gemm64<<<dim3(24, 32), 256, 0, stream>>>(xb, Wb, qkb, kT_b, vT_b);
    qkv_gemm64<<<dim3(24, 32), 256, 0, stream>>>(xb, Wb, qkb, kT_b, vT_b);
    qkv_gemm64<<<dim3(24, 32), 256, 0, stream>>>(xb, Wb, qkb, kT_b, vT_b);
    qkv_gemm64<<<dim3(24, 32), 256, 0, stream>>>(xb, Wb, qkb, kT_b, vT_b);
    qkv_gemm64<<<dim3(24, 32), 256, 0, stream>>>(xb, Wb, qkb, kT_b, vT_b);
    attn_fused<<<dim3(NCHUNK, NH), 256, 0, stream>>>(qkb, kT_b, vT_b, attnb);
    out_gemm64<<<dim3(16, 32), 256, 0, stream>>>(attnb, Wob, out);
}

// Round 8
// 130.750 us; speedup vs baseline: 1.5981x; 1.5981x over previous
//
#include <hip/hip_runtime.h>
#include <hip/hip_bf16.h>

typedef __attribute__((ext_vector_type(8))) short short8;
typedef __attribute__((ext_vector_type(4))) float floatx4;
typedef __attribute__((ext_vector_type(8))) unsigned short ushortx8;
typedef __attribute__((ext_vector_type(4))) unsigned short ushortx4;
typedef unsigned short u16;

#define NH 16
#define SEQ 2048
#define CHUNK 128
#define NCHUNK 16

__device__ __forceinline__ u16 f2bf(float f) {
    union { float f; unsigned u; } v; v.f = f;
    unsigned r = v.u + 0x7fffu + ((v.u >> 16) & 1u);
    return (u16)(r >> 16);
}
__device__ __forceinline__ float bf2f(u16 u) {
    union { unsigned u; float f; } v; v.u = ((unsigned)u) << 16;
    return v.f;
}
__device__ __forceinline__ void gl_lds16(const u16* g, u16* l) {
    __builtin_amdgcn_global_load_lds(
        (const __attribute__((address_space(1))) void*)g,
        (__attribute__((address_space(3))) void*)l,
        16, 0, 0);
}

// ---------------------------------------------------------------------------
// Kernel 0: fp32 -> bf16 of x, Wq|Wk|Wv (fused rows), Wo. ~48 MB traffic,
// BW-bound ~8 us.
// ---------------------------------------------------------------------------
__global__ __launch_bounds__(256)
void convert_all(const float* __restrict__ x,  const float* __restrict__ Wq,
                 const float* __restrict__ Wk, const float* __restrict__ Wv,
                 const float* __restrict__ Wo,
                 u16* __restrict__ xb, u16* __restrict__ Wb, u16* __restrict__ Wob)
{
    const int total4 = 1572864;  // 6M floats / 4
    for (int idx = blockIdx.x * 256 + threadIdx.x; idx < total4; idx += gridDim.x * 256) {
        const float4* src; u16* dst; int off;
        if (idx < 524288)       { src = (const float4*)x;  dst = xb;            off = idx; }
        else if (idx < 786432)  { src = (const float4*)Wq; dst = Wb;            off = idx - 524288; }
        else if (idx < 1048576) { src = (const float4*)Wk; dst = Wb + 1048576;  off = idx - 786432; }
        else if (idx < 1310720) { src = (const float4*)Wv; dst = Wb + 2097152;  off = idx - 1048576; }
        else                    { src = (const float4*)Wo; dst = Wob;           off = idx - 1310720; }
        float4 v = src[off];
        ushortx4 u = { f2bf(v.x), f2bf(v.y), f2bf(v.z), f2bf(v.w) };
        *(ushortx4*)(dst + (size_t)off * 4) = u;
    }
}

// ---------------------------------------------------------------------------
// Kernel 1: fused QKV GEMM, 64x128 tile (768 blocks), BK=64.
// R8: __launch_bounds__(256,4) -> 4 blocks/CU (LDS 24KB, VGPR ~76 < 128 cap)
// for more latency hiding at the vmcnt(0) barrier drain. Body = R6.
// Epilogue: q row-major+elu; k row-major+elu AND kT; v -> vT only.
// ---------------------------------------------------------------------------
__global__ __launch_bounds__(256, 4)
void qkv_gemm64(const u16* __restrict__ A, const u16* __restrict__ Bm,
                u16* __restrict__ qkb, u16* __restrict__ kT_b, u16* __restrict__ vT_b)
{
    __shared__ u16 As[64 * 64];
    __shared__ u16 Bs[128 * 64];
    const int n0 = blockIdx.x * 128, m0 = blockIdx.y * 64;
    const int t = threadIdx.x;
    const int lane = t & 63, wave = t >> 6;
    const int ln = lane & 15, q4 = lane >> 4;
    const int wm = (wave >> 1) * 32, wn = (wave & 1) * 64;
    const int r_in = t >> 3;
    const int csw = (((t & 7) ^ (r_in & 7)) << 3);

    const u16* Ag = A + (size_t)(m0 + r_in) * 1024 + csw;
    const u16* Bg = Bm + (size_t)(n0 + r_in) * 1024 + csw;

    floatx4 acc[2][4];
#pragma unroll
    for (int i = 0; i < 2; i++)
#pragma unroll
        for (int j = 0; j < 4; j++) acc[i][j] = (floatx4)0.0f;

    for (int k0 = 0; k0 < 1024; k0 += 64) {
        if (k0) __syncthreads();
        gl_lds16(Ag, &As[t * 8]);
        gl_lds16(Ag + 32 * 1024, &As[2048 + t * 8]);
#pragma unroll
        for (int i = 0; i < 4; i++)
            gl_lds16(Bg + (size_t)i * 32 * 1024, &Bs[i * 2048 + t * 8]);
        Ag += 64; Bg += 64;
        __syncthreads();
#pragma unroll
        for (int s = 0; s < 2; s++) {
            const int rc = (((s * 4 + q4) ^ (ln & 7)) << 3);
            short8 af[2], bfr[4];
#pragma unroll
            for (int i = 0; i < 2; i++)
                af[i] = *(const short8*)&As[(wm + i * 16 + ln) * 64 + rc];
#pragma unroll
            for (int j = 0; j < 4; j++)
                bfr[j] = *(const short8*)&Bs[(wn + j * 16 + ln) * 64 + rc];
#pragma unroll
            for (int i = 0; i < 2; i++)
#pragma unroll
                for (int j = 0; j < 4; j++)
                    acc[i][j] = __builtin_amdgcn_mfma_f32_16x16x32_bf16(af[i], bfr[j], acc[i][j], 0, 0, 0);
        }
    }
    const int grp = n0 >> 10;  // 0=q 1=k 2=v (block-uniform)
#pragma unroll
    for (int i = 0; i < 2; i++)
#pragma unroll
        for (int j = 0; j < 4; j++) {
            const int mb = m0 + wm + i * 16 + q4 * 4;
            const int n = n0 + wn + j * 16 + ln;
            const int nh = n & 1023, h = nh >> 6, e = nh & 63;
            float vals[4];
#pragma unroll
            for (int r = 0; r < 4; r++) {
                float v = acc[i][j][r];
                if (grp < 2) v = (v > 0.f) ? (v + 1.f) : __expf(v);
                vals[r] = v;
            }
            if (grp == 0) {
#pragma unroll
                for (int r = 0; r < 4; r++) qkb[(size_t)(mb + r) * 2048 + nh] = f2bf(vals[r]);
            } else if (grp == 1) {
#pragma unroll
                for (int r = 0; r < 4; r++) qkb[(size_t)(mb + r) * 2048 + 1024 + nh] = f2bf(vals[r]);
                ushortx4 u = { f2bf(vals[0]), f2bf(vals[1]), f2bf(vals[2]), f2bf(vals[3]) };
                *(ushortx4*)&kT_b[(size_t)(h * 64 + e) * 2048 + mb] = u;
            } else {
                ushortx4 u = { f2bf(vals[0]), f2bf(vals[1]), f2bf(vals[2]), f2bf(vals[3]) };
                *(ushortx4*)&vT_b[(size_t)(h * 64 + e) * 2048 + mb] = u;
            }
        }
}

// ---------------------------------------------------------------------------
// Kernel 2: FUSED chunk-state + attention per (c,h). grid (16,16).
// R8: __launch_bounds__(256,2) — the old (256,1) capped occupancy at 1 wave/EU
// (4 waves/CU = 1 block/CU). LDS 59.6KB allows 2 blocks/CU; VGPR ~130 < 256.
// Body = R6.
// ---------------------------------------------------------------------------
__global__ __launch_bounds__(256, 2)
void attn_fused(const u16* __restrict__ qkb, const u16* __restrict__ kT_b,
                const u16* __restrict__ vT_b, u16* __restrict__ attnb)
{
    __shared__ __align__(16) u16 smem[29824];   // 59648 B
    u16* kT_s  = smem;           // [64][128]  phase-A staging
    u16* vT_s  = smem + 8192;    // [64][128]  phase-A staging
    u16* vT_l  = smem;           // [64][128]  own chunk (over kT_s)
    u16* q_l   = smem + 8192;    // [128][64]  (over vT_s)
    u16* k_l   = smem + 16384;   // [128][64]
    u16* P_l   = smem + 8192;    // [128][128] swizzled (over q_l+k_l when dead)
    u16* kvT_l = smem + 24576;   // [64][72]
    float* kpref  = (float*)(smem + 29184);  // [64]
    float* denom2 = (float*)(smem + 29312);  // [2][128]

    const int c = blockIdx.x, h = blockIdx.y;
    const int t = threadIdx.x;
    const int lane = t & 63, w = t >> 6;
    const int ln = lane & 15, q4 = lane >> 4;

    // ---- phase A: prefix KV state + kpref over chunks 0..c-1 ----
    floatx4 sacc[4];
    floatx4 sksum = (floatx4)0.0f;
#pragma unroll
    for (int j = 0; j < 4; j++) sacc[j] = (floatx4)0.0f;
    const short one_bf = (short)0x3F80;
    const short8 a_ones = { one_bf, one_bf, one_bf, one_bf,
                            one_bf, one_bf, one_bf, one_bf };
    for (int cp = 0; cp < c; cp++) {
        __syncthreads();               // prev chunk's LDS reads done
#pragma unroll
        for (int i = 0; i < 4; i++) {
            const int d0 = w * 16 + i * 4 + (lane >> 4);
            const int cc = lane & 15;
            const size_t gsrc = (size_t)(h * 64 + d0) * 2048 + cp * 128 + ((cc ^ (d0 & 7)) << 3);
            gl_lds16(kT_b + gsrc, &kT_s[(w * 16 + i * 4) * 128 + lane * 8]);
            gl_lds16(vT_b + gsrc, &vT_s[(w * 16 + i * 4) * 128 + lane * 8]);
        }
        __syncthreads();               // drain DMA
#pragma unroll
        for (int ks = 0; ks < 4; ks++) {
            const int rc = (((ks * 4 + q4) ^ (ln & 7)) << 3);
            short8 af = *(const short8*)&kT_s[(w * 16 + ln) * 128 + rc];
            sksum = __builtin_amdgcn_mfma_f32_16x16x32_bf16(a_ones, af, sksum, 0, 0, 0);
#pragma unroll
            for (int j = 0; j < 4; j++) {
                short8 bfr = *(const short8*)&vT_s[(j * 16 + ln) * 128 + rc];
                sacc[j] = __builtin_amdgcn_mfma_f32_16x16x32_bf16(af, bfr, sacc[j], 0, 0, 0);
            }
        }
    }
    __syncthreads();                   // phase-A LDS reads done; regions reusable

    // ---- own-chunk staging (async) + publish kvT/kpref ----
#pragma unroll
    for (int i = 0; i < 4; i++) {
        const int l = i * 32 + w * 8 + (lane >> 3);
        const int cc = lane & 7;
        const size_t gq = (size_t)(c * CHUNK + l) * 2048 + h * 64 + ((cc ^ (l & 7)) << 3);
        gl_lds16(qkb + gq,        &q_l[(i * 32 + w * 8) * 64 + lane * 8]);
        gl_lds16(qkb + gq + 1024, &k_l[(i * 32 + w * 8) * 64 + lane * 8]);
        const int d0 = w * 16 + i * 4 + (lane >> 4);
        const int cv = lane & 15;
        gl_lds16(vT_b + (size_t)(h * 64 + d0) * 2048 + c * 128 + ((cv ^ (d0 & 7)) << 3),
                 &vT_l[(w * 16 + i * 4) * 128 + lane * 8]);
    }
    // kvT_l[e][d] = KV_pref[d][e]
#pragma unroll
    for (int j = 0; j < 4; j++) {
        const int e = j * 16 + ln;
        ushortx4 u = { f2bf(sacc[j][0]), f2bf(sacc[j][1]), f2bf(sacc[j][2]), f2bf(sacc[j][3]) };
        *(ushortx4*)&kvT_l[e * 72 + w * 16 + q4 * 4] = u;
    }
    if (q4 == 0) kpref[w * 16 + ln] = sksum[0];  // ones-MFMA: col d = w*16+ln
    __syncthreads();                   // drains own DMAs; kvT/kpref visible

    // ---- P = QK^T : wave quadrant, 64x64, K=64 ----
    const int pm = (w >> 1) * 64, pn = (w & 1) * 64;
    floatx4 pacc[4][4];
#pragma unroll
    for (int i = 0; i < 4; i++)
#pragma unroll
        for (int j = 0; j < 4; j++) pacc[i][j] = (floatx4)0.0f;
#pragma unroll
    for (int s = 0; s < 2; s++) {
        const int rc = (((s * 4 + q4) ^ (ln & 7)) << 3);
        short8 af[4], bfr[4];
#pragma unroll
        for (int i = 0; i < 4; i++)
            af[i] = *(const short8*)&q_l[(pm + i * 16 + ln) * 64 + rc];
#pragma unroll
        for (int j = 0; j < 4; j++)
            bfr[j] = *(const short8*)&k_l[(pn + j * 16 + ln) * 64 + rc];
#pragma unroll
        for (int i = 0; i < 4; i++)
#pragma unroll
            for (int j = 0; j < 4; j++)
                pacc[i][j] = __builtin_amdgcn_mfma_f32_16x16x32_bf16(af[i], bfr[j], pacc[i][j], 0, 0, 0);
    }
    // ---- causal mask + rowsum (intra denominator) ----
#pragma unroll
    for (int i = 0; i < 4; i++)
#pragma unroll
        for (int r = 0; r < 4; r++) {
            int rowi = pm + i * 16 + q4 * 4 + r;
            float rs = 0.f;
#pragma unroll
            for (int j = 0; j < 4; j++) {
                int col = pn + j * 16 + ln;
                float p = pacc[i][j][r];
                if (col > rowi) p = 0.f;
                pacc[i][j][r] = p;
                rs += p;
            }
#pragma unroll
            for (int off = 1; off < 16; off <<= 1) rs += __shfl_xor(rs, off, 64);
            if (ln == 0) denom2[(w & 1) * 128 + rowi] = rs;
        }
    // ---- O_inter = Q @ KV_pref ----
    const int ob = w * 32;
    floatx4 oacc[2][4];
#pragma unroll
    for (int i = 0; i < 2; i++)
#pragma unroll
        for (int j = 0; j < 4; j++) oacc[i][j] = (floatx4)0.0f;
#pragma unroll
    for (int s = 0; s < 2; s++) {
        const int rc = (((s * 4 + q4) ^ (ln & 7)) << 3);
        short8 af[2], bfr[4];
#pragma unroll
        for (int i2 = 0; i2 < 2; i2++)
            af[i2] = *(const short8*)&q_l[(ob + i2 * 16 + ln) * 64 + rc];
#pragma unroll
        for (int j = 0; j < 4; j++)
            bfr[j] = *(const short8*)&kvT_l[(j * 16 + ln) * 72 + s * 32 + q4 * 8];
#pragma unroll
        for (int i2 = 0; i2 < 2; i2++)
#pragma unroll
            for (int j = 0; j < 4; j++)
                oacc[i2][j] = __builtin_amdgcn_mfma_f32_16x16x32_bf16(af[i2], bfr[j], oacc[i2][j], 0, 0, 0);
    }
    __syncthreads();   // denom rowsums visible; q/k/kvT MFMA reads done
    // ---- denominator inter part: q_i . kpref ----
    if (t < 128) {
        float s = 0.f;
#pragma unroll
        for (int c8 = 0; c8 < 8; c8++) {
            ushortx8 v8 = *(const ushortx8*)&q_l[t * 64 + ((c8 ^ (t & 7)) << 3)];
#pragma unroll
            for (int jj = 0; jj < 8; jj++) s += bf2f(v8[jj]) * kpref[c8 * 8 + jj];
        }
        denom2[t] += s;
    }
    __syncthreads();   // q_l reads done; safe to overwrite with P
    // ---- write masked P, bf16, XOR-swizzled [128][128] ----
#pragma unroll
    for (int i = 0; i < 4; i++)
#pragma unroll
        for (int j = 0; j < 4; j++)
#pragma unroll
            for (int r = 0; r < 4; r++) {
                int rowi = pm + i * 16 + q4 * 4 + r;
                int col = pn + j * 16 + ln;
                P_l[rowi * 128 + (col ^ ((rowi & 7) << 3))] = f2bf(pacc[i][j][r]);
            }
    __syncthreads();
    // ---- O_intra = P @ V : causal skip (ks <= wave) ----
    for (int ks = 0; ks <= w; ks++) {
        short8 af[2], bfr[4];
#pragma unroll
        for (int i2 = 0; i2 < 2; i2++) {
            const int row = ob + i2 * 16 + ln;
            af[i2] = *(const short8*)&P_l[row * 128 + ((((ks * 4 + q4) ^ (row & 7))) << 3)];
        }
        const int rc = (((ks * 4 + q4) ^ (ln & 7)) << 3);
#pragma unroll
        for (int j = 0; j < 4; j++)
            bfr[j] = *(const short8*)&vT_l[(j * 16 + ln) * 128 + rc];
#pragma unroll
        for (int i2 = 0; i2 < 2; i2++)
#pragma unroll
            for (int j = 0; j < 4; j++)
                oacc[i2][j] = __builtin_amdgcn_mfma_f32_16x16x32_bf16(af[i2], bfr[j], oacc[i2][j], 0, 0, 0);
    }
    // ---- normalize + store ----
#pragma unroll
    for (int i2 = 0; i2 < 2; i2++)
#pragma unroll
        for (int j = 0; j < 4; j++)
#pragma unroll
            for (int r = 0; r < 4; r++) {
                int rowi = ob + i2 * 16 + q4 * 4 + r;
                int e = j * 16 + ln;
                float den = denom2[rowi] + denom2[128 + rowi];
                den = fmaxf(den, 1e-6f);
                float val = oacc[i2][j][r] / den;
                attnb[(size_t)(c * CHUNK + rowi) * 1024 + h * 64 + e] = f2bf(val);
            }
}

// ---------------------------------------------------------------------------
// Kernel 3: out = attn @ Wo^T, 64x64 tile (512 blocks), fp32 out.
// R8: __launch_bounds__(256,4) -> 4 blocks/CU (LDS 16KB, tiny VGPR).
// ---------------------------------------------------------------------------
__global__ __launch_bounds__(256, 4)
void out_gemm64(const u16* __restrict__ A, const u16* __restrict__ Bm,
                float* __restrict__ out)
{
    __shared__ u16 As[64 * 64];
    __shared__ u16 Bs[64 * 64];
    const int n0 = blockIdx.x * 64, m0 = blockIdx.y * 64;
    const int t = threadIdx.x;
    const int lane = t & 63, wave = t >> 6;
    const int ln = lane & 15, q4 = lane >> 4;
    const int wm = (wave >> 1) * 32, wn = (wave & 1) * 32;
    const int r_in = t >> 3;
    const int csw = (((t & 7) ^ (r_in & 7)) << 3);

    const u16* Ag = A + (size_t)(m0 + r_in) * 1024 + csw;
    const u16* Bg = Bm + (size_t)(n0 + r_in) * 1024 + csw;

    floatx4 acc[2][2];
#pragma unroll
    for (int i = 0; i < 2; i++)
#pragma unroll
        for (int j = 0; j < 2; j++) acc[i][j] = (floatx4)0.0f;

    for (int k0 = 0; k0 < 1024; k0 += 64) {
        if (k0) __syncthreads();
        gl_lds16(Ag, &As[t * 8]);
        gl_lds16(Ag + 32 * 1024, &As[2048 + t * 8]);
        gl_lds16(Bg, &Bs[t * 8]);
        gl_lds16(Bg + 32 * 1024, &Bs[2048 + t * 8]);
        Ag += 64; Bg += 64;
        __syncthreads();
#pragma unroll
        for (int s = 0; s < 2; s++) {
            const int rc = (((s * 4 + q4) ^ (ln & 7)) << 3);
            short8 af[2], bfr[2];
#pragma unroll
            for (int i = 0; i < 2; i++)
                af[i] = *(const short8*)&As[(wm + i * 16 + ln) * 64 + rc];
#pragma unroll
            for (int j = 0; j < 2; j++)
                bfr[j] = *(const short8*)&Bs[(wn + j * 16 + ln) * 64 + rc];
#pragma unroll
            for (int i = 0; i < 2; i++)
#pragma unroll
                for (int j = 0; j < 2; j++)
                    acc[i][j] = __builtin_amdgcn_mfma_f32_16x16x32_bf16(af[i], bfr[j], acc[i][j], 0, 0, 0);
        }
    }
#pragma unroll
    for (int i = 0; i < 2; i++)
#pragma unroll
        for (int j = 0; j < 2; j++)
#pragma unroll
            for (int r = 0; r < 4; r++) {
                int m = m0 + wm + i * 16 + q4 * 4 + r;
                int n = n0 + wn + j * 16 + ln;
                out[(size_t)m * 1024 + n] = acc[i][j][r];
            }
}

// ---------------------------------------------------------------------------
// Workspace (32 MB of >=256 MB):
//   xb @ 0 (4MB) | Wb @ 4 (6MB) | Wob @ 10 (2MB) | qkb @ 12 (8MB)
//   kT_b @ 20 (4MB) | vT_b @ 24 (4MB) | attnb @ 28 (4MB)
// ---------------------------------------------------------------------------
extern "C" void kernel_launch(void* const* d_in, const int* in_sizes, int n_in,
                              void* d_out, int out_size, void* d_ws, size_t ws_size,
                              hipStream_t stream)
{
    const float* x  = (const float*)d_in[0];
    const float* Wq = (const float*)d_in[1];
    const float* Wk = (const float*)d_in[2];
    const float* Wv = (const float*)d_in[3];
    const float* Wo = (const float*)d_in[4];
    float* out = (float*)d_out;

    char* ws = (char*)d_ws;
    const size_t MB = 1024 * 1024;
    u16* xb    = (u16*)(ws);
    u16* Wb    = (u16*)(ws + 4 * MB);
    u16* Wob   = (u16*)(ws + 10 * MB);
    u16* qkb   = (u16*)(ws + 12 * MB);
    u16* kT_b  = (u16*)(ws + 20 * MB);
    u16* vT_b  = (u16*)(ws + 24 * MB);
    u16* attnb = (u16*)(ws + 28 * MB);

    convert_all<<<2048, 256, 0, stream>>>(x, Wq, Wk, Wv, Wo, xb, Wb, Wob);
    qkv_gemm64<<<dim3(24, 32), 256, 0, stream>>>(xb, Wb, qkb, kT_b, vT_b);
    attn_fused<<<dim3(NCHUNK, NH), 256, 0, stream>>>(qkb, kT_b, vT_b, attnb);
    out_gemm64<<<dim3(16, 32), 256, 0, stream>>>(attnb, Wob, out);
}